// Round 1
// 481.295 us; speedup vs baseline: 1.0755x; 1.0755x over previous
//
#include <hip/hip_runtime.h>
#include <hip/hip_fp16.h>

// Rotation_9242769622431 — round 4: bank-conflict-free rotation mapping.
// rocprof forensics (round 3): SQ_LDS_BANK_CONFLICT = 7.24e7/dispatch ≈ 56% of
// kernel cycles; VALUBusy 20%, HBM 24%. Cause: wave lanes = 64 random pair
// columns of the SAME row -> ~4-way conflicts on every rotation LDS op.
// Fix: lane = row, wave w owns pairs [16w,16w+16). Rotation access tile[l][a]
// has wave-uniform column a and per-lane row l; stride 129 (odd) gives bank
// (l + a) % 32 -> exactly 2 lanes/bank = free on CDNA4. Pair params are
// broadcast from lane pp via v_readlane (no LDS param traffic, scalar addrs).
// Intra-layer pairs are disjoint columns; waves own disjoint pairs -> only
// one __syncthreads per layer (8 total). fp32 math identical to round 3.

typedef unsigned int uint32;

#define DIM    4096
#define GROUP  128
#define KROT   8
#define NGROUP 32
#define TPAD   (GROUP + 1)   // odd stride -> rotation phase conflict-free

__device__ __forceinline__ float bf16_to_f(unsigned short u) {
    union { uint32 i; float f; } v; v.i = ((uint32)u) << 16; return v.f;
}
__device__ __forceinline__ unsigned short f_to_bf16(float f) {
    union { float f; uint32 i; } v; v.f = f;
    uint32 x = v.i;
    return (unsigned short)((x + 0x7fffu + ((x >> 16) & 1u)) >> 16);  // RNE
}
__device__ __forceinline__ float fp16_to_f(unsigned short u) {
    __half h = __ushort_as_half(u); return __half2float(h);
}
__device__ __forceinline__ unsigned short f_to_fp16(float f) {
    return __half_as_ushort(__float2half_rn(f));
}
__device__ __forceinline__ float bcast_f(float x, int lane) {
    return __uint_as_float(__builtin_amdgcn_readlane(__float_as_uint(x), lane));
}

// flag: 0 = fp32, 1 = bf16, 2 = fp16   (unchanged from round 3 — it worked)
__global__ __launch_bounds__(256) void detect_dtype(const uint32* __restrict__ scw,
                                                    int* __restrict__ flag) {
    __shared__ int cbf[256], cfp16[256];
    int b = 0, h = 0;
    for (int i = threadIdx.x; i < 2048; i += 256) {   // 8 KB: in-bounds for all dtypes
        uint32 lo = scw[i] & 0xffffu;
        b += (lo >= 0x3F00u && lo <= 0x3FC0u);        // bf16 in [0.5, 1.5]
        h += (lo >= 0x3800u && lo <= 0x3E00u);        // fp16 in [0.5, 1.5]
    }
    cbf[threadIdx.x] = b; cfp16[threadIdx.x] = h;
    __syncthreads();
    for (int s = 128; s > 0; s >>= 1) {
        if (threadIdx.x < s) { cbf[threadIdx.x] += cbf[threadIdx.x + s];
                               cfp16[threadIdx.x] += cfp16[threadIdx.x + s]; }
        __syncthreads();
    }
    if (threadIdx.x == 0)
        *flag = (cbf[0] > 1024) ? 1 : ((cfp16[0] > 1024) ? 2 : 0);
}

// ---------------------------------------------------------------------------
// Block = (group g, 64-row tile), 256 threads = 4 waves.
//   lane l (= tid & 63) owns row l of the tile for the rotation phase.
//   wave w (= tid >> 6) owns pairs [16w, 16w+16) of the 64 pairs per layer.
// Per layer: 16 iterations; pair tuple (a,b,c,s) broadcast from lane (pp) via
// readlane -> wave-uniform column index -> bank = (l + a) % 32 -> 2-way = free.
// ---------------------------------------------------------------------------
__global__ __launch_bounds__(256) void rotate_direct(
    const void* __restrict__ Xv,
    const int*  __restrict__ pairs,
    const void* __restrict__ thetav,
    const void* __restrict__ scalesv,
    void* __restrict__ Outv,
    const int* __restrict__ flagp, int defflag)
{
    __shared__ float tile[64][TPAD];
    __shared__ float scl[GROUP];
    const int g    = blockIdx.x;
    const int row0 = blockIdx.y * 64;
    const int tid  = threadIdx.x;
    const int dt   = flagp ? *flagp : defflag;
    const int l    = tid & 63;          // lane id == row owned in rotation phase
    const int w    = tid >> 6;          // wave id
    const int pmine = w * 16 + (l & 15); // the pair this lane's params describe

    // preload scales (before first barrier)
    if (tid < GROUP) {
        int c = g * GROUP + tid;
        scl[tid] = (dt == 1) ? bf16_to_f(((const unsigned short*)scalesv)[c])
                 : (dt == 2) ? fp16_to_f(((const unsigned short*)scalesv)[c])
                 : ((const float*)scalesv)[c];
    }

    // per-lane param set: pair pmine for every layer. Lanes 0-15 of wave w hold
    // the 16 tuples the wave will broadcast; lanes 16-63 hold redundant copies.
    int A[KROT], B[KROT]; float C[KROT], S[KROT];
    #pragma unroll
    for (int k = 0; k < KROT; ++k) {
        A[k] = pairs[k * DIM + g * GROUP + 2 * pmine];       // local col 0..127
        B[k] = pairs[k * DIM + g * GROUP + 2 * pmine + 1];
        int ti = k * (DIM / 2) + g * (GROUP / 2) + pmine;
        float th = (dt == 1) ? bf16_to_f(((const unsigned short*)thetav)[ti])
                 : (dt == 2) ? fp16_to_f(((const unsigned short*)thetav)[ti])
                 : ((const float*)thetav)[ti];
        C[k] = __builtin_cosf(th);
        S[k] = __builtin_sinf(th);
    }

    // ---- load tile (global-coalesced; LDS writes ~4-way, small cost) ----
    if (dt == 0) {
        const float4* X4 = (const float4*)Xv;
        for (int i = tid; i < 64 * 32; i += 256) {
            int r = i >> 5, c4 = i & 31;
            float4 v = X4[(size_t)(row0 + r) * (DIM / 4) + g * (GROUP / 4) + c4];
            tile[r][c4 * 4 + 0] = v.x; tile[r][c4 * 4 + 1] = v.y;
            tile[r][c4 * 4 + 2] = v.z; tile[r][c4 * 4 + 3] = v.w;
        }
    } else {
        const uint4* X4 = (const uint4*)Xv;     // 8 halves per load
        for (int i = tid; i < 64 * 16; i += 256) {
            int r = i >> 4, c8 = i & 15;
            uint4 wv = X4[(size_t)(row0 + r) * (DIM / 8) + g * (GROUP / 8) + c8];
            uint32 ws[4] = { wv.x, wv.y, wv.z, wv.w };
            #pragma unroll
            for (int h2 = 0; h2 < 4; ++h2) {
                unsigned short lo = (unsigned short)(ws[h2] & 0xffffu);
                unsigned short hi = (unsigned short)(ws[h2] >> 16);
                tile[r][c8 * 8 + 2 * h2]     = (dt == 1) ? bf16_to_f(lo) : fp16_to_f(lo);
                tile[r][c8 * 8 + 2 * h2 + 1] = (dt == 1) ? bf16_to_f(hi) : fp16_to_f(hi);
            }
        }
    }
    __syncthreads();

    // ---- 8 Givens layers, conflict-free ----
    // Within a layer: the 64 pairs are disjoint columns (permutation) and the
    // 4 waves own disjoint pair subsets -> no races; barrier only per layer.
    #pragma unroll
    for (int k = 0; k < KROT; ++k) {
        #pragma unroll
        for (int pp = 0; pp < 16; ++pp) {
            int   a = __builtin_amdgcn_readlane(A[k], pp);   // wave-uniform
            int   b = __builtin_amdgcn_readlane(B[k], pp);
            float c = bcast_f(C[k], pp);
            float s = bcast_f(S[k], pp);
            float xa = tile[l][a], xb = tile[l][b];
            tile[l][a] = c * xa - s * xb;
            tile[l][b] = s * xa + c * xb;
        }
        __syncthreads();
    }

    // ---- scale + store (last layer's barrier already synced the tile) ----
    if (dt == 0) {
        float4* O4 = (float4*)Outv;
        for (int i = tid; i < 64 * 32; i += 256) {
            int r = i >> 5, c4 = i & 31;
            float4 v;
            v.x = tile[r][c4 * 4 + 0] * scl[c4 * 4 + 0];
            v.y = tile[r][c4 * 4 + 1] * scl[c4 * 4 + 1];
            v.z = tile[r][c4 * 4 + 2] * scl[c4 * 4 + 2];
            v.w = tile[r][c4 * 4 + 3] * scl[c4 * 4 + 3];
            O4[(size_t)(row0 + r) * (DIM / 4) + g * (GROUP / 4) + c4] = v;
        }
    } else {
        uint4* O4 = (uint4*)Outv;
        for (int i = tid; i < 64 * 16; i += 256) {
            int r = i >> 4, c8 = i & 15;
            uint32 ws[4];
            #pragma unroll
            for (int h2 = 0; h2 < 4; ++h2) {
                float lo = tile[r][c8 * 8 + 2 * h2]     * scl[c8 * 8 + 2 * h2];
                float hi = tile[r][c8 * 8 + 2 * h2 + 1] * scl[c8 * 8 + 2 * h2 + 1];
                unsigned short ulo = (dt == 1) ? f_to_bf16(lo) : f_to_fp16(lo);
                unsigned short uhi = (dt == 1) ? f_to_bf16(hi) : f_to_fp16(hi);
                ws[h2] = (uint32)ulo | ((uint32)uhi << 16);
            }
            uint4 wv; wv.x = ws[0]; wv.y = ws[1]; wv.z = ws[2]; wv.w = ws[3];
            O4[(size_t)(row0 + r) * (DIM / 8) + g * (GROUP / 8) + c8] = wv;
        }
    }
}

extern "C" void kernel_launch(void* const* d_in, const int* in_sizes, int n_in,
                              void* d_out, int out_size, void* d_ws, size_t ws_size,
                              hipStream_t stream) {
    const void* x      = d_in[0];
    const int*  pairs  = (const int*)d_in[1];
    const void* theta  = d_in[2];
    const void* scales = d_in[3];

    const int N = in_sizes[0] / DIM;       // rows (fp16 count; /2 if fp32 — grid
    const int nrowtiles = N / 64;          // still covers all rows via flag path)

    int* flag = nullptr;
    if (d_ws != nullptr && ws_size >= sizeof(int)) {
        flag = (int*)d_ws;
        detect_dtype<<<1, 256, 0, stream>>>((const uint32*)scales, flag);
    }
    rotate_direct<<<dim3(NGROUP, nrowtiles), 256, 0, stream>>>(
        x, pairs, theta, scales, d_out, flag, 0);
}